// Round 1
// baseline (9286.266 us; speedup 1.0000x reference)
//
#include <hip/hip_runtime.h>
#include <hip/hip_bf16.h>

// ---------------- problem constants ----------------
#define DMODEL 768
#define DINNER 1536
#define NROWS  4096      // B*L
#define SEQLEN 2048
#define DSTATE 16
#define DTRANK 48
#define DXP    80        // DTRANK + 2*DSTATE
#define NVOCAB 32000

typedef unsigned short u16;
typedef __attribute__((ext_vector_type(8))) short  short8;
typedef __attribute__((ext_vector_type(4))) float  floatx4;

__device__ __forceinline__ u16 f2bf(float f) {
    unsigned u = __builtin_bit_cast(unsigned, f);
    unsigned r = 0x7FFFu + ((u >> 16) & 1u);   // RNE
    return (u16)((u + r) >> 16);
}
__device__ __forceinline__ float bf2f(u16 h) {
    unsigned u = ((unsigned)h) << 16;
    return __builtin_bit_cast(float, u);
}
__device__ __forceinline__ float siluf(float x) { return x / (1.f + expf(-x)); }

// ---------------- split fp32 -> bf16 hi/lo ----------------
__global__ void k_split(const float* __restrict__ in, u16* __restrict__ hi,
                        u16* __restrict__ lo, int n4) {
    int i = blockIdx.x * blockDim.x + threadIdx.x;
    int stride = gridDim.x * blockDim.x;
    for (; i < n4; i += stride) {
        float4 f = ((const float4*)in)[i];
        u16 h0 = f2bf(f.x), h1 = f2bf(f.y), h2 = f2bf(f.z), h3 = f2bf(f.w);
        ushort4 hv; hv.x = h0; hv.y = h1; hv.z = h2; hv.w = h3;
        ((ushort4*)hi)[i] = hv;
        if (lo) {
            ushort4 lv;
            lv.x = f2bf(f.x - bf2f(h0));
            lv.y = f2bf(f.y - bf2f(h1));
            lv.z = f2bf(f.z - bf2f(h2));
            lv.w = f2bf(f.w - bf2f(h3));
            ((ushort4*)lo)[i] = lv;
        }
    }
}

// ---------------- embedding gather ----------------
__global__ void k_embed(const int* __restrict__ ids, const float* __restrict__ emb,
                        float* __restrict__ x) {
    int row = blockIdx.x;
    int id = ids[row];
    const float* src = emb + (size_t)id * DMODEL;
    float* dst = x + (size_t)row * DMODEL;
    for (int c = threadIdx.x; c < DMODEL; c += blockDim.x) dst[c] = src[c];
}

// ---------------- causal conv(k=4) + silu, plus silu(z) ----------------
__global__ void k_conv_silu(const float* __restrict__ xz, const float* __restrict__ cw,
                            const float* __restrict__ cb, float* __restrict__ ssm,
                            float* __restrict__ sz) {
    int row = blockIdx.y;                                  // 0..4095
    int d   = blockIdx.x * blockDim.x + threadIdx.x;       // 0..1535
    int t   = row & (SEQLEN - 1);
    float acc = cb[d];
    #pragma unroll
    for (int k = 0; k < 4; ++k) {
        int tt = t + k - 3;
        if (tt >= 0) acc += xz[(size_t)(row + k - 3) * (2 * DINNER) + d] * cw[d * 4 + k];
    }
    ssm[(size_t)row * DINNER + d] = siluf(acc);
    float z = xz[(size_t)row * (2 * DINNER) + DINNER + d];
    sz[(size_t)row * DINNER + d] = siluf(z);
}

// ---------------- selective scan ----------------
// block: 256 thr = 16 d x 16 s ; grid: 2 * (1536/16) = 192
__global__ void k_scan(const float* __restrict__ dtp, const float* __restrict__ bdt,
                       const float* __restrict__ ssm, const float* __restrict__ dbl,
                       const float* __restrict__ Alog, const float* __restrict__ Dpv,
                       const float* __restrict__ sz, float* __restrict__ u) {
    int blk = blockIdx.x;
    int b    = blk / (DINNER / 16);
    int dblk = blk % (DINNER / 16);
    int dl = threadIdx.x >> 4;
    int s  = threadIdx.x & 15;
    int d  = dblk * 16 + dl;
    float A  = -expf(Alog[d * DSTATE + s]);
    float Dd = Dpv[d];
    float bd = bdt[d];
    float h = 0.f;
    size_t row = (size_t)b * SEQLEN;
    for (int t = 0; t < SEQLEN; ++t, ++row) {
        float dpre = dtp[row * DINNER + d] + bd;
        float dt = fmaxf(dpre, 0.f) + log1pf(__expf(-fabsf(dpre)));  // softplus
        float xv = ssm[row * DINNER + d];
        float Bv = dbl[row * DXP + DTRANK + s];
        float Cv = dbl[row * DXP + DTRANK + DSTATE + s];
        float dA = __expf(dt * A);
        h = h * dA + dt * xv * Bv;
        float yv = h * Cv;
        yv += __shfl_xor(yv, 1);
        yv += __shfl_xor(yv, 2);
        yv += __shfl_xor(yv, 4);
        yv += __shfl_xor(yv, 8);
        if (s == 0) u[row * DINNER + d] = (yv + xv * Dd) * sz[row * DINNER + d];
    }
}

// ---------------- LayerNorm -> bf16 ----------------
__global__ void k_ln(const float* __restrict__ x, const float* __restrict__ g,
                     const float* __restrict__ bb, u16* __restrict__ out) {
    __shared__ float red[256];
    int row = blockIdx.x;
    int tid = threadIdx.x;
    const float* xr = x + (size_t)row * DMODEL;
    float v0 = xr[tid], v1 = xr[tid + 256], v2 = xr[tid + 512];
    red[tid] = v0 + v1 + v2;
    __syncthreads();
    for (int o = 128; o > 0; o >>= 1) { if (tid < o) red[tid] += red[tid + o]; __syncthreads(); }
    float mu = red[0] * (1.f / 768.f);
    __syncthreads();
    red[tid] = (v0 - mu) * (v0 - mu) + (v1 - mu) * (v1 - mu) + (v2 - mu) * (v2 - mu);
    __syncthreads();
    for (int o = 128; o > 0; o >>= 1) { if (tid < o) red[tid] += red[tid + o]; __syncthreads(); }
    float var = red[0] * (1.f / 768.f);
    float rs = rsqrtf(var + 1e-5f);
    u16* orow = out + (size_t)row * DMODEL;
    orow[tid]       = f2bf((v0 - mu) * rs * g[tid]       + bb[tid]);
    orow[tid + 256] = f2bf((v1 - mu) * rs * g[tid + 256] + bb[tid + 256]);
    orow[tid + 512] = f2bf((v2 - mu) * rs * g[tid + 512] + bb[tid + 512]);
}

// ---------------- generic MFMA GEMM: C[M][N] = A[M][K] * B[N][K]^T ----------------
// SPLIT=1: fp32-accurate via bf16 hi/lo (Ah*Bh + Al*Bh + Ah*Bl)
template<int SPLIT>
__global__ __launch_bounds__(256, 2)
void k_gemm(const u16* __restrict__ Ah, const u16* __restrict__ Al,
            const u16* __restrict__ Bh, const u16* __restrict__ Bl,
            float* __restrict__ C, int M, int N, int K, int lda, int ldb, int ldc) {
    constexpr int LDK = 40;                       // 32 + 8 pad (80B row stride)
    __shared__ __align__(16) u16 sA[2][128 * LDK];
    __shared__ __align__(16) u16 sB[2][128 * LDK];
    const int tid  = threadIdx.x;
    const int m0 = blockIdx.y * 128, n0 = blockIdx.x * 128;
    const int wave = tid >> 6, lane = tid & 63;
    const int wm = (wave >> 1) * 64, wn = (wave & 1) * 64;
    const int fr = lane & 15, fq = lane >> 4;

    floatx4 acc[4][4];
    #pragma unroll
    for (int i = 0; i < 4; ++i)
        #pragma unroll
        for (int j = 0; j < 4; ++j)
            #pragma unroll
            for (int r = 0; r < 4; ++r) acc[i][j][r] = 0.f;

    for (int kt = 0; kt < K; kt += 32) {
        __syncthreads();
        #pragma unroll
        for (int half = 0; half < 2; ++half) {
            int c  = tid + half * 256;       // 0..511
            int rr = c >> 2;                 // tile row 0..127
            int ko = (c & 3) * 8;            // k offset in tile
            int gk = kt + ko;
            {   // A tile(s)
                int gm = m0 + rr;
                short8 vh = {0,0,0,0,0,0,0,0}, vl = {0,0,0,0,0,0,0,0};
                if (gm < M) {
                    const u16* p = Ah + (size_t)gm * lda + gk;
                    if (gk + 8 <= K) vh = *(const short8*)p;
                    else { for (int jj = 0; jj < 8; ++jj) if (gk + jj < K) vh[jj] = (short)p[jj]; }
                    if (SPLIT) {
                        const u16* q = Al + (size_t)gm * lda + gk;
                        if (gk + 8 <= K) vl = *(const short8*)q;
                        else { for (int jj = 0; jj < 8; ++jj) if (gk + jj < K) vl[jj] = (short)q[jj]; }
                    }
                }
                *(short8*)&sA[0][rr * LDK + ko] = vh;
                if (SPLIT) *(short8*)&sA[1][rr * LDK + ko] = vl;
            }
            {   // B tile(s)
                int gn = n0 + rr;
                short8 vh = {0,0,0,0,0,0,0,0}, vl = {0,0,0,0,0,0,0,0};
                if (gn < N) {
                    const u16* p = Bh + (size_t)gn * ldb + gk;
                    if (gk + 8 <= K) vh = *(const short8*)p;
                    else { for (int jj = 0; jj < 8; ++jj) if (gk + jj < K) vh[jj] = (short)p[jj]; }
                    if (SPLIT) {
                        const u16* q = Bl + (size_t)gn * ldb + gk;
                        if (gk + 8 <= K) vl = *(const short8*)q;
                        else { for (int jj = 0; jj < 8; ++jj) if (gk + jj < K) vl[jj] = (short)q[jj]; }
                    }
                }
                *(short8*)&sB[0][rr * LDK + ko] = vh;
                if (SPLIT) *(short8*)&sB[1][rr * LDK + ko] = vl;
            }
        }
        __syncthreads();

        short8 aH[4], bH[4];
        #pragma unroll
        for (int i = 0; i < 4; ++i) aH[i] = *(const short8*)&sA[0][(wm + i * 16 + fr) * LDK + fq * 8];
        #pragma unroll
        for (int j = 0; j < 4; ++j) bH[j] = *(const short8*)&sB[0][(wn + j * 16 + fr) * LDK + fq * 8];
        #pragma unroll
        for (int i = 0; i < 4; ++i)
            #pragma unroll
            for (int j = 0; j < 4; ++j)
                acc[i][j] = __builtin_amdgcn_mfma_f32_16x16x32_bf16(aH[i], bH[j], acc[i][j], 0, 0, 0);
        if (SPLIT) {
            short8 aL[4], bL[4];
            #pragma unroll
            for (int i = 0; i < 4; ++i) aL[i] = *(const short8*)&sA[1][(wm + i * 16 + fr) * LDK + fq * 8];
            #pragma unroll
            for (int j = 0; j < 4; ++j) bL[j] = *(const short8*)&sB[1][(wn + j * 16 + fr) * LDK + fq * 8];
            #pragma unroll
            for (int i = 0; i < 4; ++i)
                #pragma unroll
                for (int j = 0; j < 4; ++j) {
                    acc[i][j] = __builtin_amdgcn_mfma_f32_16x16x32_bf16(aL[i], bH[j], acc[i][j], 0, 0, 0);
                    acc[i][j] = __builtin_amdgcn_mfma_f32_16x16x32_bf16(aH[i], bL[j], acc[i][j], 0, 0, 0);
                }
        }
    }
    // C/D layout (verified m89/m91): col = lane&15, row = (lane>>4)*4 + reg
    #pragma unroll
    for (int i = 0; i < 4; ++i)
        #pragma unroll
        for (int j = 0; j < 4; ++j) {
            int m = m0 + wm + i * 16 + fq * 4;
            int n = n0 + wn + j * 16 + fr;
            if (n < N) {
                #pragma unroll
                for (int r = 0; r < 4; ++r)
                    if (m + r < M) C[(size_t)(m + r) * ldc + n] = acc[i][j][r];
            }
        }
}

// ---------------- launch ----------------
extern "C" void kernel_launch(void* const* d_in, const int* in_sizes, int n_in,
                              void* d_out, int out_size, void* d_ws, size_t ws_size,
                              hipStream_t stream) {
    const int*   ids   = (const int*)d_in[0];
    const float* emb   = (const float*)d_in[1];
    const float* W_in  = (const float*)d_in[2];
    const float* cw    = (const float*)d_in[3];
    const float* cb    = (const float*)d_in[4];
    const float* W_x   = (const float*)d_in[5];
    const float* W_dt  = (const float*)d_in[6];
    const float* b_dt  = (const float*)d_in[7];
    const float* Alog  = (const float*)d_in[8];
    const float* Dp    = (const float*)d_in[9];
    const float* W_out = (const float*)d_in[10];
    const float* ln_g  = (const float*)d_in[11];
    const float* ln_b  = (const float*)d_in[12];
    const float* W_hd  = (const float*)d_in[13];

    char* ws = (char*)d_ws;
    float* xb   = (float*)(ws + 0);            // 4096x768   f32
    float* xz   = (float*)(ws + 12582912);     // 4096x3072  f32 (reused: dtp, u, head bf16)
    float* ssm  = (float*)(ws + 62914560);     // 4096x1536  f32
    float* szb  = (float*)(ws + 88080384);     // 4096x1536  f32
    float* dbl  = (float*)(ws + 113246208);    // 4096x80    f32
    u16*   Ahb  = (u16*)(ws + 114556928);      // 4096x1536  bf16
    u16*   Alb  = (u16*)(ws + 127139840);
    u16*   Bhb  = (u16*)(ws + 139722752);      // 3072x768   bf16
    u16*   Blb  = (u16*)(ws + 144441344);
    u16*   dblh = (u16*)(ws + 149159936);      // 4096x80    bf16
    u16*   dbll = (u16*)(ws + 149815296);      // total 150,470,656 B

    float* dtp = xz;                           // xz region dead after conv
    float* ub  = xz + (size_t)NROWS * DINNER;
    u16*   lnh = Ahb;                          // reuse after last layer
    u16*   hdh = (u16*)xz;                     // 32000x768 bf16 = 49.15MB <= xz region

    k_embed<<<NROWS, 256, 0, stream>>>(ids, emb, xb);

    for (int i = 0; i < 4; ++i) {
        // in_proj: xz = x @ W_in^T   (M=4096,N=3072,K=768)
        k_split<<<2048, 256, 0, stream>>>(xb, Ahb, Alb, NROWS * DMODEL / 4);
        k_split<<<2048, 256, 0, stream>>>(W_in + (size_t)i * 3072 * DMODEL, Bhb, Blb, 3072 * DMODEL / 4);
        k_gemm<1><<<dim3(24, 32), 256, 0, stream>>>(Ahb, Alb, Bhb, Blb, xz,
                                                    NROWS, 3072, DMODEL, DMODEL, DMODEL, 3072);
        // conv + silu, silu(z)
        k_conv_silu<<<dim3(6, NROWS), 256, 0, stream>>>(xz, cw + (size_t)i * DINNER * 4,
                                                        cb + (size_t)i * DINNER, ssm, szb);
        // x_proj: dbl = ssm @ W_x^T  (N=80,K=1536)
        k_split<<<2048, 256, 0, stream>>>(ssm, Ahb, Alb, NROWS * DINNER / 4);
        k_split<<<480, 256, 0, stream>>>(W_x + (size_t)i * DXP * DINNER, Bhb, Blb, DXP * DINNER / 4);
        k_gemm<1><<<dim3(1, 32), 256, 0, stream>>>(Ahb, Alb, Bhb, Blb, dbl,
                                                   NROWS, DXP, DINNER, DINNER, DINNER, DXP);
        // dt_proj: dtp = dbl[:, :48] @ W_dt^T  (N=1536,K=48, lda=80)
        k_split<<<320, 256, 0, stream>>>(dbl, dblh, dbll, NROWS * DXP / 4);
        k_split<<<72, 256, 0, stream>>>(W_dt + (size_t)i * DINNER * DTRANK, Bhb, Blb, DINNER * DTRANK / 4);
        k_gemm<1><<<dim3(12, 32), 256, 0, stream>>>(dblh, dbll, Bhb, Blb, dtp,
                                                    NROWS, DINNER, DTRANK, DXP, DTRANK, DINNER);
        // selective scan (+softplus, +D skip, *silu(z))
        k_scan<<<192, 256, 0, stream>>>(dtp, b_dt + (size_t)i * DINNER, ssm, dbl,
                                        Alog + (size_t)i * DINNER * DSTATE,
                                        Dp + (size_t)i * DINNER, szb, ub);
        // out_proj: x = u @ W_out^T  (N=768,K=1536)
        k_split<<<2048, 256, 0, stream>>>(ub, Ahb, Alb, NROWS * DINNER / 4);
        k_split<<<2048, 256, 0, stream>>>(W_out + (size_t)i * DMODEL * DINNER, Bhb, Blb, DMODEL * DINNER / 4);
        k_gemm<1><<<dim3(6, 32), 256, 0, stream>>>(Ahb, Alb, Bhb, Blb, xb,
                                                   NROWS, DMODEL, DINNER, DINNER, DINNER, DMODEL);
    }

    k_ln<<<NROWS, 256, 0, stream>>>(xb, ln_g, ln_b, lnh);
    k_split<<<8192, 256, 0, stream>>>(W_hd, hdh, (u16*)nullptr, NVOCAB * DMODEL / 4);
    // head: logits = ln(x) @ W_head^T  (plain bf16 — error ~0.16% of max << 2% bar)
    k_gemm<0><<<dim3(250, 32), 256, 0, stream>>>(lnh, nullptr, hdh, nullptr, (float*)d_out,
                                                 NROWS, NVOCAB, DMODEL, DMODEL, DMODEL, NVOCAB);
}